// Round 11
// baseline (204.665 us; speedup 1.0000x reference)
//
#include <hip/hip_runtime.h>

typedef __attribute__((ext_vector_type(8))) short short8;
typedef __attribute__((ext_vector_type(2))) float float2_t;
typedef __attribute__((ext_vector_type(4))) float float4_t;
typedef __attribute__((ext_vector_type(4))) int int4_t;
typedef __attribute__((ext_vector_type(2))) unsigned uint2_t;
typedef __attribute__((ext_vector_type(4))) unsigned uint4_t;

#define CH_STRIDE 4096        // 64*64 spatial per channel
#define IMG_STRIDE 524288     // 128 channels * 4096
#define HW 4096
#define V520 520              // Vt row stride (shorts); 1040B rows keep 16B align

static __device__ __forceinline__ float bitsf(unsigned u) { return __builtin_bit_cast(float, u); }
static __device__ __forceinline__ unsigned bitsu(float f) { return __builtin_bit_cast(unsigned, f); }

// f32 pair -> packed 2x bf16 (RNE), one VALU op (R10 win, kept).
static __device__ __forceinline__ unsigned cvt_pk(float lo, float hi) {
    unsigned r;
    asm("v_cvt_pk_bf16_f32 %0, %1, %2" : "=v"(r) : "v"(lo), "v"(hi));
    return r;
}

// Fused CSWin block: flash attention (S^T = K*Q^T, permlane P-exchange,
// O^T = V^T*P^T) + depthwise 3x3 conv rpe from LDS-resident V, one launch.
//
// R11 = R10 base + TWO CHUNKS PER BARRIER PHASE (4 phases x 2 chunks).
// Ledger: every pipe <=27% busy; wall is dependency stall with convoyed
// waves (16-wave blocks barrier-synced -> ~2 independent phase-streams/CU).
// The one never-varied axis: independent work per phase. Each wave now gets
// two register-disjoint S->exp2->pack->permlane->PV chains between barriers
// (only the final acc/lsum accumulates serialize, ~30cy) so the compiler can
// interleave them to fill the ~300cy chain gaps. Barriers 16 -> 8.
// Wave-parity stagger (cA = 2ph + (wv&1)) splits the barrier-release burst
// across the two Kc buffers. Staging stays distributed + 2-deep prefetched
// (R8 lesson: loads for phase p+2 issue at end of phase p, staged end of p+1).
// LDS: Kc 2x5.1KB + Vt 33.3KB = 43.5KB; x2 blocks = 87KB <= 160KB.
// RISK (load-bearing): VGPR must stay <= 64 (interleaved bodies raise peak
// pressure; >64 halves waves/SIMD -> R9-style regression). Verify counter.
// Pre-commit: neutral with VGPR<=64 -> source-level dependency-fill is
// exhausted; stop at best kernel next round.
__global__ __launch_bounds__(1024) void cswin_fused(
    const float* __restrict__ temp, const float* __restrict__ cw,
    const float* __restrict__ cb, float* __restrict__ out)
{
    __shared__ short Kc[2][64 * 40];   // [chunk-parity][key][d] pad-40
    __shared__ short Vt[32 * V520];    // [d][l] full 512-key window, persistent

    int bx = blockIdx.x;
    int nw = bx >> 6;          // window column 0..7 (high bits: XCD L2 locality)
    int r  = bx & 63;
    int b  = r >> 2;           // batch 0..15
    int n  = r & 3;            // head 0..3

    int t    = threadIdx.x;
    int wv   = t >> 6;         // wave 0..15
    int lane = t & 63;
    int mr   = lane & 15;
    int q    = lane >> 4;

    const float* tq = temp + (size_t)b * 3 * IMG_STRIDE + (size_t)(n * 32) * CH_STRIDE + nw * 8;
    const float* tk = tq + IMG_STRIDE;
    const float* tv = tk + IMG_STRIDE;

    int row0 = wv * 32;        // this wave's 32 q-rows (16 waves x 32 = 512)
    const float qscale = 0.2550348889072310f;   // (1/sqrt(32)) * log2(e)

    // Q fragments (B-operand): lane holds Q[row0+qt*16+mr][q*8+j] * qscale
    short8 Qf[2];
    #pragma unroll
    for (int qt = 0; qt < 2; ++qt) {
        int l = row0 + qt * 16 + mr;
        int sp = (l >> 3) * 64 + (l & 7);
        float f[8];
        #pragma unroll
        for (int j = 0; j < 8; ++j)
            f[j] = tq[(q * 8 + j) * CH_STRIDE + sp] * qscale;
        uint4_t up = { cvt_pk(f[0], f[1]), cvt_pk(f[2], f[3]),
                       cvt_pk(f[4], f[5]), cvt_pk(f[6], f[7]) };
        Qf[qt] = __builtin_bit_cast(short8, up);
    }

    float4_t zero4 = {0.f, 0.f, 0.f, 0.f};
    float4_t acc[2][2];
    #pragma unroll
    for (int dt = 0; dt < 2; ++dt)
        #pragma unroll
        for (int qt = 0; qt < 2; ++qt)
            acc[dt][qt] = zero4;
    float lsum[2] = {0.f, 0.f};

    // loader mapping: 1024 threads = 32 d x 32 key-slots; thread (ld,seg)
    // handles keys seg, seg+32 of each chunk. Two chunks per phase:
    // kx0/vx0 = even chunk, kx1/vx1 = odd chunk of the next phase.
    int ld  = t >> 5;          // channel d 0..31
    int seg = t & 31;
    const float* tkld = tk + (size_t)ld * CH_STRIDE;
    const float* tvld = tv + (size_t)ld * CH_STRIDE;

    float kx0[2], vx0[2], kx1[2], vx1[2];
    #pragma unroll
    for (int i = 0; i < 2; ++i) {      // load chunks 0 and 1
        int lb0 = seg + 32 * i;
        int sp0 = (lb0 >> 3) * 64 + (lb0 & 7);
        kx0[i] = tkld[sp0]; vx0[i] = tvld[sp0];
        int lb1 = 64 + seg + 32 * i;
        int sp1 = (lb1 >> 3) * 64 + (lb1 & 7);
        kx1[i] = tkld[sp1]; vx1[i] = tvld[sp1];
    }
    {   // prologue: stage chunks 0 (->Kc[0]) and 1 (->Kc[1])
        unsigned pk = cvt_pk(kx0[0], kx0[1]);
        Kc[0][(seg)      * 40 + ld] = (short)(pk & 0xffffu);
        Kc[0][(seg + 32) * 40 + ld] = (short)(pk >> 16);
        unsigned pv = cvt_pk(vx0[0], vx0[1]);
        Vt[ld * V520 + seg]      = (short)(pv & 0xffffu);
        Vt[ld * V520 + seg + 32] = (short)(pv >> 16);
        pk = cvt_pk(kx1[0], kx1[1]);
        Kc[1][(seg)      * 40 + ld] = (short)(pk & 0xffffu);
        Kc[1][(seg + 32) * 40 + ld] = (short)(pk >> 16);
        pv = cvt_pk(vx1[0], vx1[1]);
        Vt[ld * V520 + 64 + seg]      = (short)(pv & 0xffffu);
        Vt[ld * V520 + 64 + seg + 32] = (short)(pv >> 16);
    }
    #pragma unroll
    for (int i = 0; i < 2; ++i) {      // issue loads for chunks 2,3 (phase 1)
        int lb0 = 128 + seg + 32 * i;
        int sp0 = (lb0 >> 3) * 64 + (lb0 & 7);
        kx0[i] = tkld[sp0]; vx0[i] = tvld[sp0];
        int lb1 = 192 + seg + 32 * i;
        int sp1 = (lb1 >> 3) * 64 + (lb1 & 7);
        kx1[i] = tkld[sp1]; vx1[i] = tvld[sp1];
    }

    int cfirst = wv & 1;       // wave-parity chunk order within a phase

    #pragma unroll 1
    for (int ph = 0; ph < 4; ++ph) {
        __syncthreads();       // publishes this phase's Kc/Vt staging

        #pragma unroll
        for (int s = 0; s < 2; ++s) {
            int cc = 2 * ph + (cfirst ^ s);      // this wave's s-th chunk
            const short* Kb = Kc[cc & 1];
            #pragma unroll
            for (int g = 0; g < 2; ++g) {
                // S^T tiles: D[m=key][n=qrow], keys g*32..g*32+31 of chunk cc
                short8 KaA = *reinterpret_cast<const short8*>(&Kb[((2 * g) * 16 + mr) * 40 + q * 8]);
                short8 KaB = *reinterpret_cast<const short8*>(&Kb[((2 * g + 1) * 16 + mr) * 40 + q * 8]);
                unsigned pa0[2], pa1[2], pb0[2], pb1[2];
                #pragma unroll
                for (int qt = 0; qt < 2; ++qt) {
                    float4_t sA = __builtin_amdgcn_mfma_f32_16x16x32_bf16(KaA, Qf[qt], zero4, 0, 0, 0);
                    float4_t sB = __builtin_amdgcn_mfma_f32_16x16x32_bf16(KaB, Qf[qt], zero4, 0, 0, 0);
                    float eA0 = __builtin_amdgcn_exp2f(sA.x), eA1 = __builtin_amdgcn_exp2f(sA.y);
                    float eA2 = __builtin_amdgcn_exp2f(sA.z), eA3 = __builtin_amdgcn_exp2f(sA.w);
                    float eB0 = __builtin_amdgcn_exp2f(sB.x), eB1 = __builtin_amdgcn_exp2f(sB.y);
                    float eB2 = __builtin_amdgcn_exp2f(sB.z), eB3 = __builtin_amdgcn_exp2f(sB.w);
                    lsum[qt] += ((eA0 + eA1) + (eA2 + eA3)) + ((eB0 + eB1) + (eB2 + eB3));
                    // pack pairs with one v_perm each (truncation): [lo16=e_even, hi16=e_odd]
                    pa0[qt] = __builtin_amdgcn_perm(bitsu(eA1), bitsu(eA0), 0x07060302u);
                    pa1[qt] = __builtin_amdgcn_perm(bitsu(eA3), bitsu(eA2), 0x07060302u);
                    pb0[qt] = __builtin_amdgcn_perm(bitsu(eB1), bitsu(eB0), 0x07060302u);
                    pb1[qt] = __builtin_amdgcn_perm(bitsu(eB3), bitsu(eB2), 0x07060302u);
                }
                // V^T A-fragments for this 32-key group
                int base = cc * 64 + g * 32 + q * 8;
                short8 Va0 = *reinterpret_cast<const short8*>(&Vt[mr * V520 + base]);
                short8 Va1 = *reinterpret_cast<const short8*>(&Vt[(16 + mr) * V520 + base]);
                #pragma unroll
                for (int qt = 0; qt < 2; ++qt) {
                    // C-layout P (keys q*4+r) -> B-operand (keys q*8+j) in-register:
                    // word w of dest lane (q,mr) comes from lane (q&1)*32+(w>>1)*16+mr
                    // of pa (q<2) / pb (q>=2). Two swap stages, two words each.
                    uint2_t re = __builtin_amdgcn_permlane32_swap(pa0[qt], pb0[qt], 0, 0);
                    uint2_t we = __builtin_amdgcn_permlane16_swap(re.x, re.y, 0, 0);   // {w0, w2}
                    uint2_t ro = __builtin_amdgcn_permlane32_swap(pa1[qt], pb1[qt], 0, 0);
                    uint2_t wo = __builtin_amdgcn_permlane16_swap(ro.x, ro.y, 0, 0);   // {w1, w3}
                    int4_t pi = { (int)we.x, (int)wo.x, (int)we.y, (int)wo.y };
                    short8 Pb = __builtin_bit_cast(short8, pi);
                    acc[0][qt] = __builtin_amdgcn_mfma_f32_16x16x32_bf16(Va0, Pb, acc[0][qt], 0, 0, 0);
                    acc[1][qt] = __builtin_amdgcn_mfma_f32_16x16x32_bf16(Va1, Pb, acc[1][qt], 0, 0, 0);
                }
            }
        }

        if (ph < 3) {
            __syncthreads();   // all waves done reading this phase's Kc
            // stage next phase: chunks 2ph+2 (even -> Kc[0]) and 2ph+3 (-> Kc[1])
            {
                int ce = (2 * ph + 2) * 64, co = (2 * ph + 3) * 64;
                unsigned pk = cvt_pk(kx0[0], kx0[1]);
                Kc[0][(seg)      * 40 + ld] = (short)(pk & 0xffffu);
                Kc[0][(seg + 32) * 40 + ld] = (short)(pk >> 16);
                unsigned pv = cvt_pk(vx0[0], vx0[1]);
                Vt[ld * V520 + ce + seg]      = (short)(pv & 0xffffu);
                Vt[ld * V520 + ce + seg + 32] = (short)(pv >> 16);
                pk = cvt_pk(kx1[0], kx1[1]);
                Kc[1][(seg)      * 40 + ld] = (short)(pk & 0xffffu);
                Kc[1][(seg + 32) * 40 + ld] = (short)(pk >> 16);
                pv = cvt_pk(vx1[0], vx1[1]);
                Vt[ld * V520 + co + seg]      = (short)(pv & 0xffffu);
                Vt[ld * V520 + co + seg + 32] = (short)(pv >> 16);
            }
            if (ph < 2) {      // issue loads for phase ph+2's chunks
                #pragma unroll
                for (int i = 0; i < 2; ++i) {
                    int lb0 = (2 * ph + 4) * 64 + seg + 32 * i;
                    int sp0 = (lb0 >> 3) * 64 + (lb0 & 7);
                    kx0[i] = tkld[sp0]; vx0[i] = tvld[sp0];
                    int lb1 = (2 * ph + 5) * 64 + seg + 32 * i;
                    int sp1 = (lb1 >> 3) * 64 + (lb1 & 7);
                    kx1[i] = tkld[sp1]; vx1[i] = tvld[sp1];
                }
            }
        }
    }

    // softmax denominators: reduce across quads, invert
    float inv[2];
    #pragma unroll
    for (int qt = 0; qt < 2; ++qt) {
        float v = lsum[qt];
        v += __shfl_xor(v, 16);
        v += __shfl_xor(v, 32);
        inv[qt] = 1.0f / v;
    }

    // O store: lane holds O[qrow=row0+qt*16+mr][c = n*32 + dt*16 + q*4 + r]
    float* outb = out + (size_t)b * HW * 128 + nw * 8 * 128 + n * 32;
    #pragma unroll
    for (int qt = 0; qt < 2; ++qt) {
        int l = row0 + qt * 16 + mr;
        size_t basep = (size_t)((l >> 3) * 64 + (l & 7)) * 128;
        #pragma unroll
        for (int dt = 0; dt < 2; ++dt) {
            float4_t o = acc[dt][qt] * inv[qt];
            *reinterpret_cast<float4_t*>(outb + basep + dt * 16 + q * 4) = o;
        }
    }

    __syncthreads();   // O-stores visible block-wide; Vt complete since last barrier

    // ---- depthwise 3x3 conv + bias (window-local SAME pad) from LDS V, RMW out
    // 1024 threads = 64 h-rows x 16 channel-pairs; each thread 2 channels.
    int c2 = (t & 15) * 2;             // relative channel 0,2,..,30
    int h  = t >> 4;                   // 0..63
    float2_t outv[8];
    #pragma unroll
    for (int cc = 0; cc < 2; ++cc) {
        int c = c2 + cc;
        float w9[9];
        #pragma unroll
        for (int i = 0; i < 9; ++i) w9[i] = cw[(n * 32 + c) * 9 + i];
        float bias = cb[n * 32 + c];
        float rv[3][8];
        #pragma unroll
        for (int rr = 0; rr < 3; ++rr) {
            int hh = h - 1 + rr;
            if (hh >= 0 && hh < 64) {
                short8 u = *reinterpret_cast<const short8*>(&Vt[c * V520 + hh * 8]);
                #pragma unroll
                for (int j = 0; j < 8; ++j)
                    rv[rr][j] = bitsf(((unsigned)(unsigned short)u[j]) << 16);
            } else {
                #pragma unroll
                for (int j = 0; j < 8; ++j) rv[rr][j] = 0.f;
            }
        }
        #pragma unroll
        for (int w = 0; w < 8; ++w) {
            float o = bias;
            #pragma unroll
            for (int rr = 0; rr < 3; ++rr) {
                if (w > 0) o += rv[rr][w - 1] * w9[rr * 3 + 0];
                o += rv[rr][w] * w9[rr * 3 + 1];
                if (w < 7) o += rv[rr][w + 1] * w9[rr * 3 + 2];
            }
            outv[w][cc] = o;
        }
    }
    #pragma unroll
    for (int w = 0; w < 8; ++w) {
        size_t off = (size_t)h * 8192 + w * 128 + c2;
        float2_t cur = *reinterpret_cast<const float2_t*>(outb + off);
        cur += outv[w];
        *reinterpret_cast<float2_t*>(outb + off) = cur;
    }
}

extern "C" void kernel_launch(void* const* d_in, const int* in_sizes, int n_in,
                              void* d_out, int out_size, void* d_ws, size_t ws_size,
                              hipStream_t stream) {
    const float* temp = (const float*)d_in[0];
    const float* cw   = (const float*)d_in[1];
    const float* cb   = (const float*)d_in[2];
    float* out = (float*)d_out;
    hipLaunchKernelGGL(cswin_fused, dim3(512), dim3(1024), 0, stream, temp, cw, cb, out);
}